// Round 2
// baseline (3183.211 us; speedup 1.0000x reference)
//
#include <hip/hip_runtime.h>

// SGM min-sum message passing, 4 directions, dense 21x21 label context.
// out = u + sum_d (L_d - u).
//   init_kernel:  out = u                       (float4 copy)
//   sweep_all:    8192 concurrent tasks (4 dirs x 2048 lines), each a single
//                 512-step DP pass; contribution (L - u) accumulated with
//                 fire-and-forget global_atomic_add_f32 (off the DP chain).
// t = 0 contributes exactly 0 -> no atomic issued for the border element.
//
// Layout: 21 lanes per task (lane = label), 3 tasks per 64-thread wave/block.
// Per-step all-to-all of 21 L values via a 24-float padded LDS row
// (wave-synchronous, no s_barrier). u/w are software-prefetched 2 steps
// ahead so global latency hides under the LDS+VALU chain (~190 cyc).

#define DLBL 21
#define SP 512
#define NB 4
#define NTASK 8192          // 4 dirs * (4 batches * 512 lines)
#define BIGF 1e30f

__global__ __launch_bounds__(256)
void init_kernel(const float* __restrict__ u, float* __restrict__ o, int n4) {
    int i = blockIdx.x * 256 + threadIdx.x;
    if (i < n4) ((float4*)o)[i] = ((const float4*)u)[i];
}

__global__ __launch_bounds__(64)
void sweep_all(const float* __restrict__ unary,
               const float* __restrict__ ew,
               const float* __restrict__ Vmat,
               float* __restrict__ out)
{
    __shared__ float xch[4][24];           // 4 task slots, pad to 24
    const int lane = threadIdx.x;          // 0..63
    const int g    = lane / DLBL;          // task-in-block 0..2 (3 = idle lane 63)
    const int s    = lane - g * DLBL;      // label 0..20
    int taskId = blockIdx.x * 3 + (g < 3 ? g : 0);
    const bool valid = (g < 3) && (taskId < NTASK);
    if (taskId >= NTASK) taskId = NTASK - 1;     // clamp; atomics predicated off

    const int dir  = taskId >> 11;         // 0..3
    const int line = taskId & 2047;        // (b, p)
    const int b    = line >> 9;
    const int p    = line & (SP - 1);
    const int axis = dir >> 1;             // 0: scan over w ; 1: scan over h
    const int rev  = dir & 1;

    // V column for this lane's output label: Vc[j] = V[j][s]
    float Vc[DLBL];
#pragma unroll
    for (int j = 0; j < DLBL; ++j) Vc[j] = Vmat[j * DLBL + s];

    const long ustep = axis ? SP : 1;
    const long ubase = axis ? ((long)(b * DLBL + s) * SP * SP + p)
                            : (((long)(b * DLBL + s) * SP + p) * SP);
    const long wbase = axis ? ((long)(b * 4 + dir) * SP * SP + p)
                            : (((long)(b * 4 + dir) * SP + p) * SP);
    const long uoff = rev ? -ustep : ustep;
    const long start = rev ? (long)(SP - 1) * ustep : 0;

    const float* up = unary + ubase + start;   // t = 0
    const float* wp = ew    + wbase + start;
    float*       op = out   + ubase + start;

    float cur = *up;                       // border: L = u, contribution 0

    // depth-2 prefetch pipeline: at top of iter t, uN0 = u[t], uN1 = u[t+1]
    const float* upp = up + 2 * uoff;      // points at t+1's successor target
    const float* wpp = wp + 2 * uoff;
    float uN0 = up[uoff],      wN0 = wp[uoff];       // t = 1
    float uN1 = up[2 * uoff],  wN1 = wp[2 * uoff];   // t = 2

    for (int t = 1; t < SP; ++t) {
        const float u_c = uN0, w_c = wN0;
        uN0 = uN1; wN0 = wN1;
        const long d = (t + 2 < SP) ? uoff : 0;      // clamp tail prefetch
        upp += d; wpp += d;
        uN1 = *upp; wN1 = *wpp;                      // prefetch t+2 (off-chain)

        // wave-synchronous all-to-all of the 21 previous L values
        xch[g][s] = cur;
        __builtin_amdgcn_wave_barrier();
        float Lp[24];
#pragma unroll
        for (int q = 0; q < 6; ++q)
            ((float4*)Lp)[q] = ((const float4*)(&xch[g][0]))[q];
        __builtin_amdgcn_wave_barrier();

        float m0 = BIGF, m1 = BIGF, m2 = BIGF;
#pragma unroll
        for (int j = 0; j < 7; ++j)   m0 = fminf(m0, fmaf(w_c, Vc[j],      Lp[j]));
#pragma unroll
        for (int j = 7; j < 14; ++j)  m1 = fminf(m1, fmaf(w_c, Vc[j],      Lp[j]));
#pragma unroll
        for (int j = 14; j < 21; ++j) m2 = fminf(m2, fmaf(w_c, Vc[j],      Lp[j]));
        cur = u_c + fminf(fminf(m0, m1), m2);

        op += uoff;
        if (valid) unsafeAtomicAdd(op, cur - u_c);   // fire-and-forget f32 add
    }
}

extern "C" void kernel_launch(void* const* d_in, const int* in_sizes, int n_in,
                              void* d_out, int out_size, void* d_ws, size_t ws_size,
                              hipStream_t stream) {
    const float* unary = (const float*)d_in[0];   // (4,1,21,512,512) f32
    const float* ew    = (const float*)d_in[1];   // (4,4,512,512)   f32
    const float* Vmat  = (const float*)d_in[2];   // (21,21)         f32
    float* o = (float*)d_out;                     // (4,1,21,512,512) f32

    const int n4 = (NB * DLBL * SP * SP) / 4;     // 5,505,024 float4s
    init_kernel<<<(n4 + 255) / 256, 256, 0, stream>>>(unary, o, n4);

    const int grid = (NTASK + 2) / 3;             // 2731 blocks, 3 tasks each
    sweep_all<<<grid, 64, 0, stream>>>(unary, ew, Vmat, o);
}

// Round 3
// 1060.495 us; speedup vs baseline: 3.0016x; 3.0016x over previous
//
#include <hip/hip_runtime.h>

// SGM min-sum message passing, 4 directions, dense 21x21 label context.
// out = sum_d L_d - 3u.
//
// Path A (ws_size >= 4 * 88MB):
//   sweep<0>: 8192 tasks (4 dirs x 2048 lines), each a 512-step DP pass.
//     L stored to a per-direction ws buffer in TRANSPOSED layout
//     idx = ((b*SP + p)*SP + pos)*21 + s  (p = line coord, pos = scan coord)
//     so the 21 lanes of a task write 21 consecutive floats per step
//     (~2 cachelines instead of 21).
//   combine: out = L0+L1+L2+L3 - 3u, coalesced along w per label plane.
//
// Path B fallback (small ws): 4 sequential kernels, dir0 plain-store to out,
//   dirs 1-3 RMW out += L - u with the o load depth-4 prefetched (no atomics;
//   each task owns its elements exclusively within a kernel; kernels are
//   stream-ordered).
//
// Task layout: 21 lanes per task (lane = label), 3 tasks per 64-thread wave.
// Per-step all-to-all of the 21 L values via a padded LDS row
// (wave-synchronous, no s_barrier). u/w (and o in MODE 2) are prefetched
// 4 steps ahead; the per-step dependence chain is LDS exchange + fma +
// 3-level min3 tree only.

#define DLBL 21
#define SP 512
#define NB 4
#define SPSP ((long)SP * SP)
#define NELEM ((long)NB * DLBL * SP * SP)   // 22,020,096 floats
#define BIGF 1e30f
#define PF 4

// MODE 0: store L to per-direction buffer, transposed layout
// MODE 1: store L to out, standard layout (fallback dir 0)
// MODE 2: out += L - u, standard layout (fallback dirs 1..3)
template<int MODE>
__global__ __launch_bounds__(64)
void sweep_kernel(const float* __restrict__ unary,
                  const float* __restrict__ ew,
                  const float* __restrict__ Vmat,
                  float* __restrict__ d0, float* __restrict__ d1,
                  float* __restrict__ d2, float* __restrict__ d3,
                  int taskBase, int nTask)
{
    __shared__ float xch[4][24];
    const int lane = threadIdx.x;          // 0..63
    const int g    = lane / DLBL;          // task-in-block 0..2 (3 = idle)
    const int s    = lane - g * DLBL;      // label 0..20
    int local = blockIdx.x * 3 + (g < 3 ? g : 0);
    const bool valid = (g < 3) && (local < nTask);
    if (local >= nTask) local = nTask - 1;
    const int taskId = taskBase + local;

    const int dir  = taskId >> 11;         // 0..3
    const int line = taskId & 2047;
    const int b    = line >> 9;
    const int p    = line & (SP - 1);      // h for axis 0, w for axis 1
    const int axis = dir >> 1;             // 0: scan over w ; 1: scan over h
    const int rev  = dir & 1;

    float Vc[DLBL];
#pragma unroll
    for (int j = 0; j < DLBL; ++j) Vc[j] = Vmat[j * DLBL + s];

    const long ustep = axis ? SP : 1;
    const long ubase = (long)(b * DLBL + s) * SPSP + (axis ? (long)p : (long)p * SP);
    const long wbase = (long)(b * 4 + dir) * SPSP + (axis ? (long)p : (long)p * SP);
    const long uoff  = rev ? -ustep : ustep;
    const long ust   = rev ? (long)(SP - 1) * ustep : 0;

    const float* up = unary + ubase + ust;     // element at pos(t=0)
    const float* wp = ew    + wbase + ust;

    float* op;
    long doff;
    if (MODE == 0) {
        float* dst = dir == 0 ? d0 : dir == 1 ? d1 : dir == 2 ? d2 : d3;
        op   = dst + ((long)(b * SP + p) * SP + (rev ? SP - 1 : 0)) * DLBL + s;
        doff = rev ? -(long)DLBL : (long)DLBL;
    } else {
        op   = d0 + ubase + ust;
        doff = uoff;
    }

    float cur = up[0];                     // border: L = u
    if (valid && MODE != 2) *op = cur;     // MODE 2 contribution at border = 0

    // depth-4 prefetch pipeline (values for t = 1..4)
    float ub0 = up[uoff],     ub1 = up[2*uoff], ub2 = up[3*uoff], ub3 = up[4*uoff];
    float wb0 = wp[uoff],     wb1 = wp[2*uoff], wb2 = wp[3*uoff], wb3 = wp[4*uoff];
    float ob0 = 0, ob1 = 0, ob2 = 0, ob3 = 0;
    if (MODE == 2) { ob0 = op[doff]; ob1 = op[2*doff]; ob2 = op[3*doff]; ob3 = op[4*doff]; }
    const float* upf = up + PF * uoff;
    const float* wpf = wp + PF * uoff;
    const float* opf = op + PF * doff;

#pragma unroll 4
    for (int t = 1; t < SP; ++t) {
        const float u_c = ub0, w_c = wb0, o_c = ob0;
        ub0 = ub1; ub1 = ub2; ub2 = ub3;
        wb0 = wb1; wb1 = wb2; wb2 = wb3;
        if (MODE == 2) { ob0 = ob1; ob1 = ob2; ob2 = ob3; }
        const bool adv = (t + PF) < SP;
        upf += adv ? uoff : 0;
        wpf += adv ? uoff : 0;
        ub3 = *upf;                        // prefetch t+4 (off-chain)
        wb3 = *wpf;
        if (MODE == 2) { opf += adv ? doff : 0; ob3 = *opf; }

        // wave-synchronous all-to-all of the 21 previous L values
        xch[g][s] = cur;
        __builtin_amdgcn_wave_barrier();
        float Lp[24];
#pragma unroll
        for (int q = 0; q < 6; ++q)
            ((float4*)Lp)[q] = ((const float4*)(&xch[g][0]))[q];
        __builtin_amdgcn_wave_barrier();

        float c[DLBL];
#pragma unroll
        for (int j = 0; j < DLBL; ++j) c[j] = fmaf(w_c, Vc[j], Lp[j]);
        float m7[7];
#pragma unroll
        for (int k = 0; k < 7; ++k)
            m7[k] = fminf(fminf(c[3*k], c[3*k+1]), c[3*k+2]);
        const float ma = fminf(fminf(m7[0], m7[1]), m7[2]);
        const float mb = fminf(fminf(m7[3], m7[4]), m7[5]);
        cur = u_c + fminf(fminf(ma, mb), m7[6]);

        op += doff;
        if (valid) {
            if (MODE == 2) *op = o_c + cur - u_c;
            else           *op = cur;
        }
    }
}

__global__ __launch_bounds__(256)
void combine_kernel(const float* __restrict__ u,
                    const float* __restrict__ l0, const float* __restrict__ l1,
                    const float* __restrict__ l2, const float* __restrict__ l3,
                    float* __restrict__ out)
{
    const long pix = (long)blockIdx.x * 256 + threadIdx.x;  // 0..1048575
    const int b = (int)(pix >> 18);
    const int h = (int)((pix >> 9) & (SP - 1));
    const int w = (int)(pix & (SP - 1));
    const long hb = ((long)(b * SP + h) * SP + w) * DLBL;   // horizontal ws idx
    const long vb = ((long)(b * SP + w) * SP + h) * DLBL;   // vertical ws idx
    const long ub = (long)b * DLBL * SPSP + (long)h * SP + w;
#pragma unroll 7
    for (int s = 0; s < DLBL; ++s) {
        const long uo = ub + (long)s * SPSP;
        out[uo] = l0[hb + s] + l1[hb + s] + l2[vb + s] + l3[vb + s]
                  - 3.0f * u[uo];
    }
}

extern "C" void kernel_launch(void* const* d_in, const int* in_sizes, int n_in,
                              void* d_out, int out_size, void* d_ws, size_t ws_size,
                              hipStream_t stream) {
    const float* unary = (const float*)d_in[0];   // (4,1,21,512,512) f32
    const float* ew    = (const float*)d_in[1];   // (4,4,512,512)   f32
    const float* Vmat  = (const float*)d_in[2];   // (21,21)         f32
    float* o = (float*)d_out;                     // (4,1,21,512,512) f32

    const size_t SZ = (size_t)NELEM * sizeof(float);   // 88,080,384 B

    if (ws_size >= 4 * SZ) {
        float* l0 = (float*)d_ws;
        float* l1 = l0 + NELEM;
        float* l2 = l1 + NELEM;
        float* l3 = l2 + NELEM;
        const int grid = (8192 + 2) / 3;              // 2731
        sweep_kernel<0><<<grid, 64, 0, stream>>>(unary, ew, Vmat,
                                                 l0, l1, l2, l3, 0, 8192);
        combine_kernel<<<(NB * SP * SP) / 256, 256, 0, stream>>>(
            unary, l0, l1, l2, l3, o);
    } else {
        const int grid = (2048 + 2) / 3;              // 683
        sweep_kernel<1><<<grid, 64, 0, stream>>>(unary, ew, Vmat,
                                                 o, nullptr, nullptr, nullptr,
                                                 0, 2048);
        for (int d = 1; d < 4; ++d)
            sweep_kernel<2><<<grid, 64, 0, stream>>>(unary, ew, Vmat,
                                                     o, nullptr, nullptr, nullptr,
                                                     d * 2048, 2048);
    }
}